// Round 1
// baseline (869.670 us; speedup 1.0000x reference)
//
#include <hip/hip_runtime.h>

#define DIM 4096
#define HD 128
#define NH 32
#define NKV 8
#define SEQ 2048
#define BATCH 2
#define MTOT (BATCH*SEQ)   // 4096 rows total
#define GK DIM             // K dim of every GEMM

typedef __bf16 bf16;
typedef __bf16 bf16x8 __attribute__((ext_vector_type(8)));
typedef float f32x4 __attribute__((ext_vector_type(4)));

__device__ __forceinline__ void gload_lds16(const void* g, void* l) {
    __builtin_amdgcn_global_load_lds(
        (const __attribute__((address_space(1))) void*)g,
        (__attribute__((address_space(3))) void*)l, 16, 0, 0);
}

// ---------------- fp32 -> bf16 flat convert (x) ----------------
__global__ __launch_bounds__(256) void conv_bf16(const float* __restrict__ in,
                                                 bf16* __restrict__ out, int n8) {
    int i = blockIdx.x * 256 + threadIdx.x;
    if (i >= n8) return;
    const float4* p = (const float4*)(in + (size_t)i * 8);
    float4 a = p[0], b = p[1];
    bf16x8 v;
    v[0]=(bf16)a.x; v[1]=(bf16)a.y; v[2]=(bf16)a.z; v[3]=(bf16)a.w;
    v[4]=(bf16)b.x; v[5]=(bf16)b.y; v[6]=(bf16)b.z; v[7]=(bf16)b.w;
    *(bf16x8*)(out + (size_t)i * 8) = v;
}

// ---------------- fp32 [K][N] -> bf16 [N][K] transpose-convert ----------------
__global__ __launch_bounds__(256) void tconv(const float* __restrict__ in,
                                             bf16* __restrict__ out, int N, int K) {
    __shared__ float t[32][33];
    int bx = blockIdx.x, by = blockIdx.y;
    int tx = threadIdx.x, ty = threadIdx.y;
    int col = bx * 32 + tx;
#pragma unroll
    for (int r = 0; r < 4; ++r) {
        int row = by * 32 + ty + r * 8;
        t[ty + r * 8][tx] = in[(size_t)row * N + col];
    }
    __syncthreads();
#pragma unroll
    for (int r = 0; r < 4; ++r) {
        int n = bx * 32 + ty + r * 8;
        int k = by * 32 + tx;
        out[(size_t)n * K + k] = (bf16)t[tx][ty + r * 8];
    }
}

// ---------------- RoPE in-place on bf16 buffer ----------------
__global__ __launch_bounds__(256) void rope_k(bf16* __restrict__ buf, int shift, int n8) {
    int i = blockIdx.x * 256 + threadIdx.x;
    if (i >= n8) return;
    size_t base = (size_t)i * 8;
    int col = (int)(base & ((1u << shift) - 1));
    int pos = (int)((base >> shift) & (SEQ - 1));
    int d0 = col & (HD - 1);
    bf16x8 v = *(const bf16x8*)(buf + base);
    float f[8];
#pragma unroll
    for (int j = 0; j < 8; ++j) f[j] = (float)v[j];
    const float nl2t = -13.287712379549449f / 64.f;  // -log2(theta)/(HD/2)
#pragma unroll
    for (int j = 0; j < 4; ++j) {
        float inv = exp2f(nl2t * (float)((d0 >> 1) + j));
        float ang = (float)pos * inv;
        float sn, cs;
        sincosf(ang, &sn, &cs);
        float x0 = f[2 * j], x1 = f[2 * j + 1];
        f[2 * j]     = x0 * cs - x1 * sn;
        f[2 * j + 1] = x0 * sn + x1 * cs;
    }
    bf16x8 ov;
#pragma unroll
    for (int j = 0; j < 8; ++j) ov[j] = (bf16)f[j];
    *(bf16x8*)(buf + base) = ov;
}

// ---------------- bf16 GEMM: C[M,N] = A[M,K] * Bt[N,K]^T  (m97 structure) ----
// MODE 0: bf16 out, ld=N.  MODE 1: fused K|V: col<1024 -> k_buf, else v^T buf.
// MODE 2: fp32 out, ld=N.
template <int MODE>
__global__ __launch_bounds__(256) void gemm_bt(const bf16* __restrict__ A,
                                               const bf16* __restrict__ Bt,
                                               void* __restrict__ out0,
                                               void* __restrict__ out1, int N) {
    __shared__ alignas(16) bf16 sA[2][128 * 32];
    __shared__ alignas(16) bf16 sB[2][128 * 32];
    const int tid = threadIdx.x;
    const int lane = tid & 63, wid = tid >> 6;
    const int wm = wid >> 1, wn = wid & 1;
    const int m0 = blockIdx.y * 128, n0 = blockIdx.x * 128;

    auto stage = [&](int buf, int kt) {
#pragma unroll
        for (int it = 0; it < 2; ++it) {
            int slot = it * 256 + tid;
            int row = slot >> 2, s = slot & 3;
            gload_lds16(A + (size_t)(m0 + row) * GK + kt * 32 + s * 8, &sA[buf][slot * 8]);
            gload_lds16(Bt + (size_t)(n0 + row) * GK + kt * 32 + s * 8, &sB[buf][slot * 8]);
        }
    };

    f32x4 acc[4][4] = {};
    stage(0, 0);
    __syncthreads();
    int cur = 0;
    for (int kt = 0; kt < GK / 32; ++kt) {
        if (kt + 1 < GK / 32) stage(cur ^ 1, kt + 1);
        bf16x8 aF[4], bF[4];
#pragma unroll
        for (int i = 0; i < 4; ++i) {
            aF[i] = *(const bf16x8*)&sA[cur][(wm * 64 + i * 16 + (lane & 15)) * 32 + (lane >> 4) * 8];
            bF[i] = *(const bf16x8*)&sB[cur][(wn * 64 + i * 16 + (lane & 15)) * 32 + (lane >> 4) * 8];
        }
#pragma unroll
        for (int mi = 0; mi < 4; ++mi)
#pragma unroll
            for (int ni = 0; ni < 4; ++ni)
                acc[mi][ni] = __builtin_amdgcn_mfma_f32_16x16x32_bf16(aF[mi], bF[ni], acc[mi][ni], 0, 0, 0);
        __syncthreads();
        cur ^= 1;
    }
#pragma unroll
    for (int mi = 0; mi < 4; ++mi) {
#pragma unroll
        for (int ni = 0; ni < 4; ++ni) {
#pragma unroll
            for (int r = 0; r < 4; ++r) {
                int row = m0 + wm * 64 + mi * 16 + (lane >> 4) * 4 + r;
                int col = n0 + wn * 64 + ni * 16 + (lane & 15);
                float v = acc[mi][ni][r];
                if constexpr (MODE == 0) {
                    ((bf16*)out0)[(size_t)row * N + col] = (bf16)v;
                } else if constexpr (MODE == 1) {
                    if (col < 1024) {
                        ((bf16*)out0)[(size_t)row * 1024 + col] = (bf16)v;
                    } else {
                        int c = col - 1024;
                        int kvh = c >> 7, d = c & 127;
                        int b = row >> 11, s = row & 2047;
                        ((bf16*)out1)[(((size_t)(b * NKV + kvh) * HD + d) << 11) + s] = (bf16)v;
                    }
                } else {
                    ((float*)out0)[(size_t)row * N + col] = v;
                }
            }
        }
    }
}

// ---------------- flash attention, GQA, causal ----------------
// grid: 2048 = b(2) * h(32) * qtile(32); 4 waves x 16 q-rows; KV tile 64.
__global__ __launch_bounds__(256) void attn_fwd(const bf16* __restrict__ q,
                                                const bf16* __restrict__ k,
                                                const bf16* __restrict__ vt,
                                                bf16* __restrict__ o) {
    __shared__ alignas(16) bf16 sK[64 * 128];   // [kv][d], XOR-swizzled source
    __shared__ alignas(16) bf16 sV[128 * 64];   // [d][kv], XOR-swizzled source
    __shared__ alignas(16) bf16 sP[4][16 * 64]; // per-wave P, swizzled
    const int tid = threadIdx.x, lane = tid & 63, wid = tid >> 6;
    const int bi = blockIdx.x;
    const int qt = 31 - (bi & 31);   // heavy (large qt) blocks first
    const int h = (bi >> 5) & 31;
    const int b = bi >> 10;
    const int kvh = h >> 2;
    const int qbase = qt * 64;

    const bf16* qp = q + ((size_t)(b * SEQ + qbase + wid * 16 + (lane & 15))) * DIM
                       + h * HD + (lane >> 4) * 8;
    bf16x8 aQ[4];
#pragma unroll
    for (int ks = 0; ks < 4; ++ks) aQ[ks] = *(const bf16x8*)(qp + ks * 32);

    f32x4 accO[8] = {};
    float m_r[4], l_r[4];
#pragma unroll
    for (int r = 0; r < 4; ++r) { m_r[r] = -1e30f; l_r[r] = 0.f; }
    const float scale = 0.08838834764831845f;  // 1/sqrt(128)

    const bf16* kb0 = k + (size_t)b * SEQ * (NKV * HD) + kvh * HD;
    const bf16* vb0 = vt + ((size_t)(b * NKV + kvh) * HD) * SEQ;

    for (int t = 0; t <= qt; ++t) {
        // stage K tile [64][128]: 16 slots/row, src slot = phys ^ (row&7)
#pragma unroll
        for (int it = 0; it < 4; ++it) {
            int slot = it * 256 + tid;
            int row = slot >> 4, s = slot & 15;
            gload_lds16(kb0 + (size_t)(t * 64 + row) * (NKV * HD) + ((s ^ (row & 7)) * 8),
                        &sK[slot * 8]);
        }
        // stage V^T tile [128][64]: 8 slots/row
#pragma unroll
        for (int it = 0; it < 4; ++it) {
            int slot = it * 256 + tid;
            int row = slot >> 3, s = slot & 7;
            gload_lds16(vb0 + (size_t)row * SEQ + t * 64 + ((s ^ (row & 7)) * 8),
                        &sV[slot * 8]);
        }
        __syncthreads();

        // QK^T: S[16q x 64kv] per wave
        f32x4 accS[4] = {};
#pragma unroll
        for (int nt = 0; nt < 4; ++nt) {
            int kr = nt * 16 + (lane & 15);
#pragma unroll
            for (int ks = 0; ks < 4; ++ks) {
                int slog = ks * 4 + (lane >> 4);
                bf16x8 bK = *(const bf16x8*)&sK[kr * 128 + ((slog ^ (kr & 7)) * 8)];
                accS[nt] = __builtin_amdgcn_mfma_f32_16x16x32_bf16(aQ[ks], bK, accS[nt], 0, 0, 0);
            }
        }

        // scale + causal mask (only diagonal tile partial)
        const bool diag = (t == qt);
        float mx[4];
#pragma unroll
        for (int r = 0; r < 4; ++r) {
            int qloc = wid * 16 + (lane >> 4) * 4 + r;
#pragma unroll
            for (int nt = 0; nt < 4; ++nt) {
                float v = accS[nt][r] * scale;
                if (diag) {
                    int kloc = nt * 16 + (lane & 15);
                    if (kloc > qloc) v = -1e30f;
                }
                accS[nt][r] = v;
                mx[r] = (nt == 0) ? v : fmaxf(mx[r], v);
            }
        }
#pragma unroll
        for (int msk = 1; msk < 16; msk <<= 1)
#pragma unroll
            for (int r = 0; r < 4; ++r)
                mx[r] = fmaxf(mx[r], __shfl_xor(mx[r], msk, 64));

        float al[4], rs[4];
#pragma unroll
        for (int r = 0; r < 4; ++r) {
            float mn = fmaxf(m_r[r], mx[r]);
            al[r] = __expf(m_r[r] - mn);
            m_r[r] = mn;
            rs[r] = 0.f;
        }
#pragma unroll
        for (int nt = 0; nt < 4; ++nt)
#pragma unroll
            for (int r = 0; r < 4; ++r) {
                float p = __expf(accS[nt][r] - m_r[r]);
                accS[nt][r] = p;
                rs[r] += p;
            }
#pragma unroll
        for (int msk = 1; msk < 16; msk <<= 1)
#pragma unroll
            for (int r = 0; r < 4; ++r)
                rs[r] += __shfl_xor(rs[r], msk, 64);
#pragma unroll
        for (int r = 0; r < 4; ++r) l_r[r] = l_r[r] * al[r] + rs[r];
#pragma unroll
        for (int d2 = 0; d2 < 8; ++d2)
#pragma unroll
            for (int r = 0; r < 4; ++r) accO[d2][r] *= al[r];

        // write P (bf16) to per-wave LDS, swizzled
#pragma unroll
        for (int nt = 0; nt < 4; ++nt)
#pragma unroll
            for (int r = 0; r < 4; ++r) {
                int row = (lane >> 4) * 4 + r;
                int col = nt * 16 + (lane & 15);
                int phys = (col >> 3) ^ (row & 7);
                sP[wid][row * 64 + phys * 8 + (col & 7)] = (bf16)accS[nt][r];
            }

        // PV: O[16 x 128] += P[16 x 64] * V[64 x 128]
        bf16x8 aP[2];
#pragma unroll
        for (int kk = 0; kk < 2; ++kk) {
            int rowp = lane & 15;
            int phys = (kk * 4 + (lane >> 4)) ^ (rowp & 7);
            aP[kk] = *(const bf16x8*)&sP[wid][rowp * 64 + phys * 8];
        }
#pragma unroll
        for (int d2 = 0; d2 < 8; ++d2) {
#pragma unroll
            for (int kk = 0; kk < 2; ++kk) {
                int dv = d2 * 16 + (lane & 15);
                int phys = (kk * 4 + (lane >> 4)) ^ (dv & 7);
                bf16x8 bV = *(const bf16x8*)&sV[dv * 64 + phys * 8];
                accO[d2] = __builtin_amdgcn_mfma_f32_16x16x32_bf16(aP[kk], bV, accO[d2], 0, 0, 0);
            }
        }
        __syncthreads();
    }

    // epilogue: normalize + store bf16
#pragma unroll
    for (int r = 0; r < 4; ++r) l_r[r] = 1.f / l_r[r];
    size_t orow = (size_t)(b * SEQ + qbase + wid * 16 + (lane >> 4) * 4) * DIM
                + h * HD + (lane & 15);
#pragma unroll
    for (int d2 = 0; d2 < 8; ++d2)
#pragma unroll
        for (int r = 0; r < 4; ++r)
            o[orow + (size_t)r * DIM + d2 * 16] = (bf16)(accO[d2][r] * l_r[r]);
}

// ---------------- launch ----------------
extern "C" void kernel_launch(void* const* d_in, const int* in_sizes, int n_in,
                              void* d_out, int out_size, void* d_ws, size_t ws_size,
                              hipStream_t stream) {
    const float* x  = (const float*)d_in[0];
    const float* wq = (const float*)d_in[1];
    const float* wk = (const float*)d_in[2];
    const float* wv = (const float*)d_in[3];
    const float* wo = (const float*)d_in[4];
    float* out = (float*)d_out;

    char* ws = (char*)d_ws;
    size_t off = 0;
    bf16* xb  = (bf16*)(ws + off); off += (size_t)MTOT * DIM * 2;   // 32 MiB (reused as attn_out)
    bf16* wqt = (bf16*)(ws + off); off += (size_t)DIM * DIM * 2;    // 32 MiB (reused as wo_t)
    bf16* wkt = (bf16*)(ws + off); off += (size_t)1024 * DIM * 2;   // 8 MiB (contiguous with wvt!)
    bf16* wvt = (bf16*)(ws + off); off += (size_t)1024 * DIM * 2;   // 8 MiB
    bf16* qb  = (bf16*)(ws + off); off += (size_t)MTOT * DIM * 2;   // 32 MiB
    bf16* kb  = (bf16*)(ws + off); off += (size_t)MTOT * 1024 * 2;  // 8 MiB
    bf16* vtb = (bf16*)(ws + off); off += (size_t)MTOT * 1024 * 2;  // 8 MiB
    bf16* ao = xb;  // attention output reuses x_bf16

    dim3 tb(32, 8);
    conv_bf16<<<(MTOT * DIM / 8) / 256, 256, 0, stream>>>(x, xb, MTOT * DIM / 8);
    tconv<<<dim3(DIM / 32, DIM / 32), tb, 0, stream>>>(wq, wqt, DIM, DIM);
    tconv<<<dim3(1024 / 32, DIM / 32), tb, 0, stream>>>(wk, wkt, 1024, DIM);
    tconv<<<dim3(1024 / 32, DIM / 32), tb, 0, stream>>>(wv, wvt, 1024, DIM);

    gemm_bt<0><<<dim3(DIM / 128, MTOT / 128), 256, 0, stream>>>(xb, wqt, qb, nullptr, DIM);
    gemm_bt<1><<<dim3(2048 / 128, MTOT / 128), 256, 0, stream>>>(xb, wkt, kb, vtb, 2048);

    rope_k<<<(MTOT * DIM / 8) / 256, 256, 0, stream>>>(qb, 12, MTOT * DIM / 8);
    rope_k<<<(MTOT * 1024 / 8) / 256, 256, 0, stream>>>(kb, 10, MTOT * 1024 / 8);

    tconv<<<dim3(DIM / 32, DIM / 32), tb, 0, stream>>>(wo, wqt, DIM, DIM);  // wo_t -> wqt space

    attn_fwd<<<BATCH * NH * (SEQ / 64), 256, 0, stream>>>(qb, kb, vtb, ao);

    gemm_bt<2><<<dim3(DIM / 128, MTOT / 128), 256, 0, stream>>>(ao, wqt, out, nullptr, DIM);
}

// Round 3
// 726.409 us; speedup vs baseline: 1.1972x; 1.1972x over previous
//
#include <hip/hip_runtime.h>

#define DIM 4096
#define HD 128
#define NH 32
#define NKV 8
#define SEQ 2048
#define BATCH 2
#define MTOT (BATCH*SEQ)   // 4096 rows total
#define GK DIM             // K dim of every GEMM

typedef __bf16 bf16;
typedef __bf16 bf16x8 __attribute__((ext_vector_type(8)));
typedef float f32x4 __attribute__((ext_vector_type(4)));

__device__ __forceinline__ void gload_lds16(const void* g, void* l) {
    __builtin_amdgcn_global_load_lds(
        (const __attribute__((address_space(1))) void*)g,
        (__attribute__((address_space(3))) void*)l, 16, 0, 0);
}

// ---------------- fp32 -> bf16 flat convert (x) ----------------
__global__ __launch_bounds__(256) void conv_bf16(const float* __restrict__ in,
                                                 bf16* __restrict__ out, int n8) {
    int i = blockIdx.x * 256 + threadIdx.x;
    if (i >= n8) return;
    const float4* p = (const float4*)(in + (size_t)i * 8);
    float4 a = p[0], b = p[1];
    bf16x8 v;
    v[0]=(bf16)a.x; v[1]=(bf16)a.y; v[2]=(bf16)a.z; v[3]=(bf16)a.w;
    v[4]=(bf16)b.x; v[5]=(bf16)b.y; v[6]=(bf16)b.z; v[7]=(bf16)b.w;
    *(bf16x8*)(out + (size_t)i * 8) = v;
}

// ---------------- fp32 [K][N] -> bf16 [N][K] transpose-convert ----------------
__global__ __launch_bounds__(256) void tconv(const float* __restrict__ in,
                                             bf16* __restrict__ out, int N, int K) {
    __shared__ float t[32][33];
    int bx = blockIdx.x, by = blockIdx.y;
    int tx = threadIdx.x, ty = threadIdx.y;
    int col = bx * 32 + tx;
#pragma unroll
    for (int r = 0; r < 4; ++r) {
        int row = by * 32 + ty + r * 8;
        t[ty + r * 8][tx] = in[(size_t)row * N + col];
    }
    __syncthreads();
#pragma unroll
    for (int r = 0; r < 4; ++r) {
        int n = bx * 32 + ty + r * 8;
        int k = by * 32 + tx;
        out[(size_t)n * K + k] = (bf16)t[tx][ty + r * 8];
    }
}

// ---------------- RoPE in-place on bf16 buffer ----------------
__global__ __launch_bounds__(256) void rope_k(bf16* __restrict__ buf, int shift, int n8) {
    int i = blockIdx.x * 256 + threadIdx.x;
    if (i >= n8) return;
    size_t base = (size_t)i * 8;
    int col = (int)(base & ((1u << shift) - 1));
    int pos = (int)((base >> shift) & (SEQ - 1));
    int d0 = col & (HD - 1);
    bf16x8 v = *(const bf16x8*)(buf + base);
    float f[8];
#pragma unroll
    for (int j = 0; j < 8; ++j) f[j] = (float)v[j];
    const float nl2t = -13.287712379549449f / 64.f;  // -log2(theta)/(HD/2)
#pragma unroll
    for (int j = 0; j < 4; ++j) {
        float inv = exp2f(nl2t * (float)((d0 >> 1) + j));
        float ang = (float)pos * inv;
        float sn, cs;
        sincosf(ang, &sn, &cs);
        float x0 = f[2 * j], x1 = f[2 * j + 1];
        f[2 * j]     = x0 * cs - x1 * sn;
        f[2 * j + 1] = x0 * sn + x1 * cs;
    }
    bf16x8 ov;
#pragma unroll
    for (int j = 0; j < 8; ++j) ov[j] = (bf16)f[j];
    *(bf16x8*)(buf + base) = ov;
}

// ---------------- bf16 GEMM: C[M,N] = A[M,K] * Bt[N,K]^T  (m97 structure) ----
// MODE 0: bf16 out, ld=N.  MODE 1: fused K|V: col<1024 -> k_buf, else v^T buf.
// MODE 2: fp32 out, ld=N.
template <int MODE>
__global__ __launch_bounds__(256) void gemm_bt(const bf16* __restrict__ A,
                                               const bf16* __restrict__ Bt,
                                               void* __restrict__ out0,
                                               void* __restrict__ out1, int N) {
    __shared__ alignas(16) bf16 sA[2][128 * 32];
    __shared__ alignas(16) bf16 sB[2][128 * 32];
    const int tid = threadIdx.x;
    const int lane = tid & 63, wid = tid >> 6;
    const int wm = wid >> 1, wn = wid & 1;
    const int m0 = blockIdx.y * 128, n0 = blockIdx.x * 128;

    auto stage = [&](int buf, int kt) {
#pragma unroll
        for (int it = 0; it < 2; ++it) {
            int slot = it * 256 + tid;
            int row = slot >> 2, s = slot & 3;
            gload_lds16(A + (size_t)(m0 + row) * GK + kt * 32 + s * 8, &sA[buf][slot * 8]);
            gload_lds16(Bt + (size_t)(n0 + row) * GK + kt * 32 + s * 8, &sB[buf][slot * 8]);
        }
    };

    f32x4 acc[4][4] = {};
    stage(0, 0);
    __syncthreads();
    int cur = 0;
    for (int kt = 0; kt < GK / 32; ++kt) {
        if (kt + 1 < GK / 32) stage(cur ^ 1, kt + 1);
        bf16x8 aF[4], bF[4];
#pragma unroll
        for (int i = 0; i < 4; ++i) {
            aF[i] = *(const bf16x8*)&sA[cur][(wm * 64 + i * 16 + (lane & 15)) * 32 + (lane >> 4) * 8];
            bF[i] = *(const bf16x8*)&sB[cur][(wn * 64 + i * 16 + (lane & 15)) * 32 + (lane >> 4) * 8];
        }
#pragma unroll
        for (int mi = 0; mi < 4; ++mi)
#pragma unroll
            for (int ni = 0; ni < 4; ++ni)
                acc[mi][ni] = __builtin_amdgcn_mfma_f32_16x16x32_bf16(aF[mi], bF[ni], acc[mi][ni], 0, 0, 0);
        __syncthreads();
        cur ^= 1;
    }
#pragma unroll
    for (int mi = 0; mi < 4; ++mi) {
#pragma unroll
        for (int ni = 0; ni < 4; ++ni) {
#pragma unroll
            for (int r = 0; r < 4; ++r) {
                int row = m0 + wm * 64 + mi * 16 + (lane >> 4) * 4 + r;
                int col = n0 + wn * 64 + ni * 16 + (lane & 15);
                float v = acc[mi][ni][r];
                if constexpr (MODE == 0) {
                    ((bf16*)out0)[(size_t)row * N + col] = (bf16)v;
                } else if constexpr (MODE == 1) {
                    if (col < 1024) {
                        ((bf16*)out0)[(size_t)row * 1024 + col] = (bf16)v;
                    } else {
                        int c = col - 1024;
                        int kvh = c >> 7, d = c & 127;
                        int b = row >> 11, s = row & 2047;
                        ((bf16*)out1)[(((size_t)(b * NKV + kvh) * HD + d) << 11) + s] = (bf16)v;
                    }
                } else {
                    ((float*)out0)[(size_t)row * N + col] = v;
                }
            }
        }
    }
}

// ---------------- flash attention, GQA, causal ----------------
// grid: 512 = b(2) * h(32) * pair(8); 8 waves x 16 q-rows = 128 q-rows/pass;
// each block runs two passes (q-tile pr and 15-pr) -> exactly 34 KV rounds each.
// K/V LDS double-buffered, prefetch-next-before-compute (m97 pattern).
__global__ __launch_bounds__(512, 4) void attn_fwd(const bf16* __restrict__ q,
                                                   const bf16* __restrict__ k,
                                                   const bf16* __restrict__ vt,
                                                   bf16* __restrict__ o) {
    __shared__ alignas(16) bf16 sK[2][64 * 128];   // [kv][d], XOR-swizzled source
    __shared__ alignas(16) bf16 sV[2][128 * 64];   // [d][kv], XOR-swizzled source
    __shared__ alignas(16) bf16 sP[8][16 * 64];    // per-wave P, swizzled
    const int tid = threadIdx.x, lane = tid & 63, wid = tid >> 6;
    const int bi = blockIdx.x;
    const int pr = bi & 7;
    const int h = (bi >> 3) & 31;
    const int b = bi >> 8;
    const int kvh = h >> 2;
    const float scale = 0.08838834764831845f;  // 1/sqrt(128)

    const bf16* kb0 = k + (size_t)b * SEQ * (NKV * HD) + kvh * HD;
    const bf16* vb0 = vt + ((size_t)(b * NKV + kvh) * HD) * SEQ;

    auto stage = [&](int bf, int tt) {
        // K tile [64][128]: 1024 16B-slots, src slot = phys ^ (row&7)
#pragma unroll
        for (int it = 0; it < 2; ++it) {
            int slot = it * 512 + tid;
            int row = slot >> 4, s = slot & 15;
            gload_lds16(kb0 + (size_t)(tt * 64 + row) * (NKV * HD) + ((s ^ (row & 7)) * 8),
                        &sK[bf][slot * 8]);
        }
        // V^T tile [128][64]: 1024 16B-slots
#pragma unroll
        for (int it = 0; it < 2; ++it) {
            int slot = it * 512 + tid;
            int row = slot >> 3, s = slot & 7;
            gload_lds16(vb0 + (size_t)row * SEQ + tt * 64 + ((s ^ (row & 7)) * 8),
                        &sV[bf][slot * 8]);
        }
    };

    auto pass = [&](int qt) {
        const int qb0 = qt * 128;
        const int nt = 2 * qt + 2;
        const bf16* qp = q + ((size_t)(b * SEQ + qb0 + wid * 16 + (lane & 15))) * DIM
                           + h * HD + (lane >> 4) * 8;
        bf16x8 aQ[4];
#pragma unroll
        for (int ks = 0; ks < 4; ++ks) aQ[ks] = *(const bf16x8*)(qp + ks * 32);

        f32x4 accO[8] = {};
        float m_r[4], l_r[4];
#pragma unroll
        for (int r = 0; r < 4; ++r) { m_r[r] = -1e30f; l_r[r] = 0.f; }

        stage(0, 0);
        __syncthreads();
        int cur = 0;
        for (int tt = 0; tt < nt; ++tt) {
            if (tt + 1 < nt) stage(cur ^ 1, tt + 1);
            // skip tiles fully above this wave's diagonal (identity contribution)
            if (tt * 64 <= qb0 + wid * 16 + 15) {
                // QK^T: S[16q x 64kv] per wave
                f32x4 accS[4] = {};
#pragma unroll
                for (int nt2 = 0; nt2 < 4; ++nt2) {
                    int kr = nt2 * 16 + (lane & 15);
#pragma unroll
                    for (int ks = 0; ks < 4; ++ks) {
                        int slog = ks * 4 + (lane >> 4);
                        bf16x8 bK = *(const bf16x8*)&sK[cur][kr * 128 + ((slog ^ (kr & 7)) * 8)];
                        accS[nt2] = __builtin_amdgcn_mfma_f32_16x16x32_bf16(aQ[ks], bK, accS[nt2], 0, 0, 0);
                    }
                }

                // scale + causal mask. Mask needed whenever tile's k_max can
                // exceed this wave's FIRST q-row (q_min), not its last.
                const bool diag = (tt * 64 + 63 > qb0 + wid * 16);
                float mx[4];
#pragma unroll
                for (int r = 0; r < 4; ++r) {
                    int qglob = qb0 + wid * 16 + (lane >> 4) * 4 + r;
#pragma unroll
                    for (int nt2 = 0; nt2 < 4; ++nt2) {
                        float v = accS[nt2][r] * scale;
                        if (diag) {
                            int kglob = tt * 64 + nt2 * 16 + (lane & 15);
                            if (kglob > qglob) v = -1e30f;
                        }
                        accS[nt2][r] = v;
                        mx[r] = (nt2 == 0) ? v : fmaxf(mx[r], v);
                    }
                }
#pragma unroll
                for (int msk = 1; msk < 16; msk <<= 1)
#pragma unroll
                    for (int r = 0; r < 4; ++r)
                        mx[r] = fmaxf(mx[r], __shfl_xor(mx[r], msk, 64));

                float al[4], rs[4];
#pragma unroll
                for (int r = 0; r < 4; ++r) {
                    float mn = fmaxf(m_r[r], mx[r]);
                    al[r] = __expf(m_r[r] - mn);
                    m_r[r] = mn;
                    rs[r] = 0.f;
                }
#pragma unroll
                for (int nt2 = 0; nt2 < 4; ++nt2)
#pragma unroll
                    for (int r = 0; r < 4; ++r) {
                        float p = __expf(accS[nt2][r] - m_r[r]);
                        accS[nt2][r] = p;
                        rs[r] += p;
                    }
#pragma unroll
                for (int msk = 1; msk < 16; msk <<= 1)
#pragma unroll
                    for (int r = 0; r < 4; ++r)
                        rs[r] += __shfl_xor(rs[r], msk, 64);
#pragma unroll
                for (int r = 0; r < 4; ++r) l_r[r] = l_r[r] * al[r] + rs[r];
#pragma unroll
                for (int d2 = 0; d2 < 8; ++d2)
#pragma unroll
                    for (int r = 0; r < 4; ++r) accO[d2][r] *= al[r];

                // write P (bf16) to per-wave LDS, swizzled
#pragma unroll
                for (int nt2 = 0; nt2 < 4; ++nt2)
#pragma unroll
                    for (int r = 0; r < 4; ++r) {
                        int row = (lane >> 4) * 4 + r;
                        int col = nt2 * 16 + (lane & 15);
                        int phys = (col >> 3) ^ (row & 7);
                        sP[wid][row * 64 + phys * 8 + (col & 7)] = (bf16)accS[nt2][r];
                    }

                // PV: O[16 x 128] += P[16 x 64] * V[64 x 128]
                bf16x8 aP[2];
#pragma unroll
                for (int kk = 0; kk < 2; ++kk) {
                    int rowp = lane & 15;
                    int phys = (kk * 4 + (lane >> 4)) ^ (rowp & 7);
                    aP[kk] = *(const bf16x8*)&sP[wid][rowp * 64 + phys * 8];
                }
#pragma unroll
                for (int d2 = 0; d2 < 8; ++d2) {
#pragma unroll
                    for (int kk = 0; kk < 2; ++kk) {
                        int dv = d2 * 16 + (lane & 15);
                        int phys = (kk * 4 + (lane >> 4)) ^ (dv & 7);
                        bf16x8 bV = *(const bf16x8*)&sV[cur][dv * 64 + phys * 8];
                        accO[d2] = __builtin_amdgcn_mfma_f32_16x16x32_bf16(aP[kk], bV, accO[d2], 0, 0, 0);
                    }
                }
            }
            __syncthreads();
            cur ^= 1;
        }

        // epilogue: normalize + store bf16
#pragma unroll
        for (int r = 0; r < 4; ++r) l_r[r] = 1.f / l_r[r];
        size_t orow = (size_t)(b * SEQ + qb0 + wid * 16 + (lane >> 4) * 4) * DIM
                    + h * HD + (lane & 15);
#pragma unroll
        for (int d2 = 0; d2 < 8; ++d2)
#pragma unroll
            for (int r = 0; r < 4; ++r)
                o[orow + (size_t)r * DIM + d2 * 16] = (bf16)(accO[d2][r] * l_r[r]);
    };

    pass(pr);
    pass(15 - pr);
}

// ---------------- launch ----------------
extern "C" void kernel_launch(void* const* d_in, const int* in_sizes, int n_in,
                              void* d_out, int out_size, void* d_ws, size_t ws_size,
                              hipStream_t stream) {
    const float* x  = (const float*)d_in[0];
    const float* wq = (const float*)d_in[1];
    const float* wk = (const float*)d_in[2];
    const float* wv = (const float*)d_in[3];
    const float* wo = (const float*)d_in[4];
    float* out = (float*)d_out;

    char* ws = (char*)d_ws;
    size_t off = 0;
    bf16* xb  = (bf16*)(ws + off); off += (size_t)MTOT * DIM * 2;   // 32 MiB (reused as attn_out)
    bf16* wqt = (bf16*)(ws + off); off += (size_t)DIM * DIM * 2;    // 32 MiB (reused as wo_t)
    bf16* wkt = (bf16*)(ws + off); off += (size_t)1024 * DIM * 2;   // 8 MiB (contiguous with wvt!)
    bf16* wvt = (bf16*)(ws + off); off += (size_t)1024 * DIM * 2;   // 8 MiB
    bf16* qb  = (bf16*)(ws + off); off += (size_t)MTOT * DIM * 2;   // 32 MiB
    bf16* kb  = (bf16*)(ws + off); off += (size_t)MTOT * 1024 * 2;  // 8 MiB
    bf16* vtb = (bf16*)(ws + off); off += (size_t)MTOT * 1024 * 2;  // 8 MiB
    bf16* ao = xb;  // attention output reuses x_bf16

    dim3 tb(32, 8);
    conv_bf16<<<(MTOT * DIM / 8) / 256, 256, 0, stream>>>(x, xb, MTOT * DIM / 8);
    tconv<<<dim3(DIM / 32, DIM / 32), tb, 0, stream>>>(wq, wqt, DIM, DIM);
    tconv<<<dim3(1024 / 32, DIM / 32), tb, 0, stream>>>(wk, wkt, 1024, DIM);
    tconv<<<dim3(1024 / 32, DIM / 32), tb, 0, stream>>>(wv, wvt, 1024, DIM);

    gemm_bt<0><<<dim3(DIM / 128, MTOT / 128), 256, 0, stream>>>(xb, wqt, qb, nullptr, DIM);
    gemm_bt<1><<<dim3(2048 / 128, MTOT / 128), 256, 0, stream>>>(xb, wkt, kb, vtb, 2048);

    rope_k<<<(MTOT * DIM / 8) / 256, 256, 0, stream>>>(qb, 12, MTOT * DIM / 8);
    rope_k<<<(MTOT * 1024 / 8) / 256, 256, 0, stream>>>(kb, 10, MTOT * 1024 / 8);

    tconv<<<dim3(DIM / 32, DIM / 32), tb, 0, stream>>>(wo, wqt, DIM, DIM);  // wo_t -> wqt space

    attn_fwd<<<BATCH * NH * 8, 512, 0, stream>>>(qb, kb, vtb, ao);

    gemm_bt<2><<<dim3(DIM / 128, MTOT / 128), 256, 0, stream>>>(ao, wqt, out, nullptr, DIM);
}